// Round 2
// baseline (102.783 us; speedup 1.0000x reference)
//
#include <hip/hip_runtime.h>

#define NUM_CLASSES 21
#define HW4   65536      // (512*512)/4 float4 groups per channel plane
#define NGRP  1048576    // 16*512*512/4 total pixel groups

typedef float f4 __attribute__((ext_vector_type(4)));
typedef int   i4 __attribute__((ext_vector_type(4)));

__global__ __launch_bounds__(256) void iou_hist_kernel(
    const f4* __restrict__ pred, const i4* __restrict__ tgt,
    unsigned int* __restrict__ hist) {
  __shared__ unsigned int sh[3 * NUM_CLASSES];
  const int tid = threadIdx.x;
  if (tid < 3 * NUM_CLASSES) sh[tid] = 0;
  __syncthreads();

  const int lane = tid & 63;
  const int g    = blockIdx.x * 256 + tid;      // exact grid: one group per thread
  const int b    = g >> 16;                     // batch index
  const int hw4  = g & (HW4 - 1);
  const int base = (b * NUM_CLASSES) << 16;     // float4 index of channel 0

  // ---- argmax over 21 channels, 4 pixels at once ----
  f4 best = __builtin_nontemporal_load(&pred[base + hw4]);
  int i0 = 0, i1 = 0, i2 = 0, i3 = 0;

#pragma unroll
  for (int cc = 1; cc < NUM_CLASSES; cc += 5) {   // 1 + 4*5 = 21
    f4 v[5];
#pragma unroll
    for (int j = 0; j < 5; ++j)
      v[j] = __builtin_nontemporal_load(&pred[base + ((cc + j) << 16) + hw4]);
#pragma unroll
    for (int j = 0; j < 5; ++j) {
      const int c = cc + j;
      if (v[j][0] > best[0]) { best[0] = v[j][0]; i0 = c; }
      if (v[j][1] > best[1]) { best[1] = v[j][1]; i1 = c; }
      if (v[j][2] > best[2]) { best[2] = v[j][2]; i2 = c; }
      if (v[j][3] > best[3]) { best[3] = v[j][3]; i3 = c; }
    }
  }

  const i4 t = __builtin_nontemporal_load(&tgt[g]);

  // match masks computed once; intersection = pred_mask & match_mask (SALU)
  const unsigned long long m0 = __ballot(i0 == t[0]);
  const unsigned long long m1 = __ballot(i1 == t[1]);
  const unsigned long long m2 = __ballot(i2 == t[2]);
  const unsigned long long m3 = __ballot(i3 == t[3]);

  unsigned int cp = 0, ct = 0, ci = 0;   // lane c owns class c's counts

#pragma unroll
  for (int c = 0; c < NUM_CLASSES; ++c) {
    const unsigned long long p0 = __ballot(i0 == c);
    const unsigned long long p1 = __ballot(i1 == c);
    const unsigned long long p2 = __ballot(i2 == c);
    const unsigned long long p3 = __ballot(i3 == c);
    const unsigned int np_ = (unsigned)__popcll(p0) + (unsigned)__popcll(p1)
                           + (unsigned)__popcll(p2) + (unsigned)__popcll(p3);
    const unsigned int ni_ = (unsigned)__popcll(p0 & m0) + (unsigned)__popcll(p1 & m1)
                           + (unsigned)__popcll(p2 & m2) + (unsigned)__popcll(p3 & m3);
    const unsigned int nt_ = (unsigned)__popcll(__ballot(t[0] == c))
                           + (unsigned)__popcll(__ballot(t[1] == c))
                           + (unsigned)__popcll(__ballot(t[2] == c))
                           + (unsigned)__popcll(__ballot(t[3] == c));
    if (lane == c) { cp = np_; ct = nt_; ci = ni_; }
  }

  // wave -> block (LDS), block -> global
  if (lane < NUM_CLASSES) {
    atomicAdd(&sh[lane], cp);
    atomicAdd(&sh[NUM_CLASSES + lane], ct);
    atomicAdd(&sh[2 * NUM_CLASSES + lane], ci);
  }
  __syncthreads();
  if (tid < 3 * NUM_CLASSES) atomicAdd(&hist[tid], sh[tid]);
}

__global__ __launch_bounds__(64) void iou_finalize_kernel(
    const unsigned int* __restrict__ hist, float* __restrict__ out) {
  const int lane = threadIdx.x;
  float iou = 0.0f;
  if (lane < NUM_CLASSES) {
    const float p = (float)hist[lane];
    const float t = (float)hist[NUM_CLASSES + lane];
    const float i = (float)hist[2 * NUM_CLASSES + lane];
    const float u = p + t - i;
    iou = (u > 0.0f) ? (i / (u + 1e-6f)) : 0.0f;
  }
#pragma unroll
  for (int off = 32; off > 0; off >>= 1) iou += __shfl_down(iou, off);
  if (lane == 0) out[0] = iou / (float)NUM_CLASSES;
}

extern "C" void kernel_launch(void* const* d_in, const int* in_sizes, int n_in,
                              void* d_out, int out_size, void* d_ws, size_t ws_size,
                              hipStream_t stream) {
  const f4* pred = (const f4*)d_in[0];
  const i4* tgt  = (const i4*)d_in[1];
  float*    out  = (float*)d_out;
  unsigned int* hist = (unsigned int*)d_ws;

  // counters must start at zero every call (ws is poisoned once, never re-poisoned)
  hipMemsetAsync(d_ws, 0, 3 * NUM_CLASSES * sizeof(unsigned int), stream);

  iou_hist_kernel<<<NGRP / 256, 256, 0, stream>>>(pred, tgt, hist);
  iou_finalize_kernel<<<1, 64, 0, stream>>>(hist, out);
}